// Round 9
// baseline (604.595 us; speedup 1.0000x reference)
//
#include <hip/hip_runtime.h>
#include <hip/hip_bf16.h>

typedef unsigned int u32;
typedef unsigned short u16;

// Geometry: B=32, IC=1, N=64, KN=128, KS=65, PAD=16, R=8, LAT=32, HW=32
#define KYP 72            // kx padded 65 -> 72 per ky row (zero weights in pad)
#define KPAD 4736         // padded to 74*64
#define NK   74           // K-tiles of 64

// d_out element offsets (fp32)
#define OUT_ATTN 0
#define OUT_QTR  262144
#define OUT_PR   524288
#define OUT_AS   524296
#define OUT_OFF  786440
#define OUT_TH   786448
#define OUT_Z    1310736

typedef __attribute__((ext_vector_type(8))) short bf16x8;
typedef __attribute__((ext_vector_type(4))) float f32x4;

__device__ const float OFFS[8] = {
  0.0f,
  0.78539816339744830961f,
  1.57079632679489661923f,
  2.35619449019234492885f,
  3.14159265358979323846f,
 -2.35619449019234492885f,
 -1.57079632679489661923f,
 -0.78539816339744830961f
};

__device__ __forceinline__ float leaky_(float v){ return v >= 0.0f ? v : 0.01f*v; }

__device__ __forceinline__ u16 f2bf(float f){
  u32 x = __float_as_uint(f);
  u32 r = (x + 0x7FFFu + ((x >> 16) & 1u)) >> 16;   // RNE
  return (u16)r;
}

__device__ __forceinline__ void gload_lds16(const void* g, void* l){
  __builtin_amdgcn_global_load_lds((const __attribute__((address_space(1))) u32*)g,
                                   (__attribute__((address_space(3))) u32*)l, 16, 0, 0);
}

#define BARRIER() { asm volatile("" ::: "memory"); __builtin_amdgcn_s_barrier(); asm volatile("" ::: "memory"); }
#define WAITV(N)  asm volatile("s_waitcnt vmcnt(" #N ")" ::: "memory")
#define LGKC(N)   { asm volatile("s_waitcnt lgkmcnt(" #N ")" ::: "memory"); __builtin_amdgcn_sched_barrier(0); }
#define SCHEDB()  __builtin_amdgcn_sched_barrier(0)

// ---------------- xshift: x(32,64,64) f32 -> xsh[s=8][b=32][row=96][col=128] bf16 ----------------
__global__ __launch_bounds__(256) void xshift_kernel(const float* __restrict__ x, u16* __restrict__ xsh){
  int t = blockIdx.x*256 + threadIdx.x;      // 8*32*96*16 = 393216 threads, 16B each
  if (t >= 393216) return;
  int c8  = t & 15;
  int u   = t >> 4;
  int row = u % 96;
  int v   = u / 96;
  int b   = v & 31;
  int s   = v >> 5;
  int iy = row - 16;
  u16 h[8];
#pragma unroll
  for (int j = 0; j < 8; ++j){
    int ix = c8*8 + j + s - 16;
    float val = 0.0f;
    if (iy >= 0 && iy < 64 && ix >= 0 && ix < 64) val = x[(b*64 + iy)*64 + ix];
    h[j] = f2bf(val);
  }
  uint4 pk;
  pk.x = (u32)h[0] | ((u32)h[1] << 16);
  pk.y = (u32)h[2] | ((u32)h[3] << 16);
  pk.z = (u32)h[4] | ((u32)h[5] << 16);
  pk.w = (u32)h[6] | ((u32)h[7] << 16);
  ((uint4*)xsh)[t] = pk;
}

// ---------------- rotate: w1(128,65,65) -> twb[n=rot*128+kn][KPAD] bf16 ----------------
__global__ __launch_bounds__(256) void rotate_kernel(const float* __restrict__ w1, u16* __restrict__ twb){
  __shared__ float wsh[4225];
  int n = blockIdx.x;          // 0..1023
  int kn = n & 127, rot = n >> 7;
  for (int i = threadIdx.x; i < 4225; i += 256) wsh[i] = w1[kn*4225 + i];
  __syncthreads();
  float th  = 0.78539816339744830961f * (float)rot;
  float cth = cosf(th), sth = sinf(th);
  for (int t = threadIdx.x; t < KPAD; t += 256){
    int ky = t / KYP, kx = t - ky*KYP;
    u16 out = 0;
    if (ky < 65 && kx < 65){
      float yy = (2.0f*(float)ky + 1.0f)/65.0f - 1.0f;
      float xx = (2.0f*(float)kx + 1.0f)/65.0f - 1.0f;
      float xs  =  cth*xx + sth*yy;
      float ysv = -sth*xx + cth*yy;
      float px = ((xs  + 1.0f)*65.0f - 1.0f)*0.5f;
      float py = ((ysv + 1.0f)*65.0f - 1.0f)*0.5f;
      float x0 = floorf(px), y0 = floorf(py);
      float wx = px - x0, wy = py - y0;
      auto samp = [&](float yf, float xf)->float{
        bool valid = (yf >= 0.0f) && (yf < 65.0f) && (xf >= 0.0f) && (xf < 65.0f);
        int yc = (int)fminf(fmaxf(yf, 0.0f), 64.0f);
        int xc = (int)fminf(fmaxf(xf, 0.0f), 64.0f);
        return valid ? wsh[yc*65 + xc] : 0.0f;
      };
      float val = samp(y0,      x0     )*(1.0f-wy)*(1.0f-wx)
                + samp(y0,      x0+1.0f)*(1.0f-wy)*wx
                + samp(y0+1.0f, x0     )*wy*(1.0f-wx)
                + samp(y0+1.0f, x0+1.0f)*wy*wx;
      out = f2bf(val);
    }
    twb[(size_t)n*KPAD + t] = out;
  }
}

// ---------------- implicit-GEMM conv, 256^2, ONE barrier per K-tile ----------------
// m = mblk*256 + lm (ox pair-major);  n = nblk*256 + ln.  512 thr = 8 waves (2M x 4N).
// Tile body: all 24 ds_reads issued up front in PINNED FIFO order (sched_barrier
// separators), 8 stage loads after, then 4 MFMA clusters gated by COUNTED
// lgkmcnt waits (12 -> 8 -> 0): read latency drains once per tile, later reads
// complete under earlier MFMA clusters. Boundary: WAITV(0)+barrier (loads were
// issued a full tile earlier). No min-waves hint: LDS caps occupancy at 1
// block/CU anyway, and regalloc may use up to 256 VGPR (avoids R8's spills).
__global__ __launch_bounds__(512) void gemm_kernel(const u16* __restrict__ xsh,
                                                   const u16* __restrict__ twb,
                                                   u16* __restrict__ ys){
  __shared__ u16 AsB[2*16384];   // [buf][256 rows][64 k] swizzled, 64 KB
  __shared__ u16 BsB[2*16384];   // 64 KB

  const int bid  = blockIdx.x;
  const int nblk = bid & 3, mblk = bid >> 2;
  const int t    = threadIdx.x;
  const int lane = t & 63, w = t >> 6;
  const int wr   = w >> 2, wn = w & 3;        // wave tile: rows wr*128, cols wn*64
  const int hi8  = (lane >> 4) << 3;

  // ---- staging thread mapping (per 8KB call c: rows c*64 + sr, cols j0e..j0e+7) ----
  const int sr  = t >> 3;
  const int j0e = (t & 7) * 8;
  const int jsw = j0e ^ ((sr & 7) << 3);      // source pre-swizzle (T2, both-sides)
  const int bg  = mblk >> 4;
  const int ox2 = (mblk & 15) * 2;
  int aOff[4];
#pragma unroll
  for (int c = 0; c < 4; ++c){
    int i  = c*64 + sr;                       // local m row
    int ox = ox2 + (i >> 7);
    int s_ = ox & 7, colb = ox & ~7;
    int b_ = (bg << 2) + ((i & 127) >> 5);
    int oy = i & 31;
    aOff[c] = ((s_*32 + b_)*96 + oy)*128 + colb;
  }
  const u16* bPtr[4];
#pragma unroll
  for (int c = 0; c < 4; ++c){
    int nloc = c*64 + sr;
    bPtr[c] = twb + (size_t)(nblk*256 + nloc)*KPAD + jsw;
  }

  auto stageA4 = [&](int ky, int kx0, u16* dstbase){
    bool pad = (ky >= 65);
    int kofs = ky*128 + kx0;
#pragma unroll
    for (int c = 0; c < 4; ++c){
      int gofs = pad ? 0 : (aOff[c] + kofs);
      gload_lds16(xsh + gofs, dstbase + c*4096 + w*512);
    }
  };
  auto stageB4 = [&](int kt, u16* dstbase){
    int ktc = (kt < NK) ? kt : (NK-1);        // ghost tile: re-read valid data
#pragma unroll
    for (int c = 0; c < 4; ++c)
      gload_lds16(bPtr[c] + ktc*64, dstbase + c*4096 + w*512);
  };

  f32x4 acc[8][4];
#pragma unroll
  for (int i = 0; i < 8; ++i)
#pragma unroll
    for (int j = 0; j < 4; ++j) acc[i][j] = (f32x4){0.f,0.f,0.f,0.f};

  bf16x8 aE[4][2], aO[4][2];   // A fragments, mh=0 / mh=1 (disjoint sets)
  bf16x8 b0[2][2], b1[2][2];   // B fragments, nh=0 / nh=1

  auto readAto = [&](int mh, const char* Ab, bf16x8 (&dst)[4][2]){
#pragma unroll
    for (int mj = 0; mj < 4; ++mj){
      int row = wr*128 + mh*64 + mj*16 + (lane & 15);
#pragma unroll
      for (int kk = 0; kk < 2; ++kk){
        int off = (row*128 + (kk*32 + hi8)*2) ^ ((row & 7) << 4);
        dst[mj][kk] = *(const bf16x8*)(Ab + off);
      }
    }
  };
  auto readBto = [&](int nh, const char* Bb, bf16x8 (&dst)[2][2]){
#pragma unroll
    for (int jn = 0; jn < 2; ++jn){
      int row = wn*64 + (nh*2 + jn)*16 + (lane & 15);
#pragma unroll
      for (int kk = 0; kk < 2; ++kk){
        int off = (row*128 + (kk*32 + hi8)*2) ^ ((row & 7) << 4);
        dst[jn][kk] = *(const bf16x8*)(Bb + off);
      }
    }
  };
  auto mfma8 = [&](bf16x8 (&Av)[4][2], bf16x8 (&Bv)[2][2], int MH, int NH){
    __builtin_amdgcn_s_setprio(1);
#pragma unroll
    for (int mj = 0; mj < 4; ++mj)
#pragma unroll
      for (int jn = 0; jn < 2; ++jn)
#pragma unroll
        for (int kk = 0; kk < 2; ++kk)
          acc[MH*4+mj][NH*2+jn] = __builtin_amdgcn_mfma_f32_16x16x32_bf16(
              Av[mj][kk], Bv[jn][kk], acc[MH*4+mj][NH*2+jn], 0, 0, 0);
    __builtin_amdgcn_s_setprio(0);
  };

  u16* const A0 = AsB;
  u16* const B0 = BsB;
  u16* const A1 = AsB + 16384;
  u16* const B1 = BsB + 16384;

  // ---- prologue: stage K-tile 0 -> buffer 0 (kt=0: ky=0, kx=jsw; no division) ----
  stageB4(0, B0);
  stageA4(0, jsw, A0);
  // incremental (ky,kx) state for the next A-stage (kt=1): k = 64 + jsw
  int kyN = (64 + jsw >= KYP) ? 1 : 0;
  int kxN = 64 + jsw - (kyN ? KYP : 0);
  WAITV(0);
  BARRIER();

  for (int kt = 0; kt < NK; ++kt){
    const char* Ab = (const char*)((kt & 1) ? A1 : A0);
    const char* Bb = (const char*)((kt & 1) ? B1 : B0);
    u16* An = (kt & 1) ? A0 : A1;
    u16* Bn = (kt & 1) ? B0 : B1;
    // ---- issue all reads in pinned FIFO order: aE(8), b0(4) | b1(4) | aO(8) ----
    readAto(0, Ab, aE);
    readBto(0, Bb, b0);
    SCHEDB();
    readBto(1, Bb, b1);
    SCHEDB();
    readAto(1, Ab, aO);
    SCHEDB();
    // ---- stage next tile (vmcnt ops; don't perturb lgkm accounting) ----
    stageB4(kt+1, Bn);
    stageA4(kyN, kxN, An);
    // ---- counted lgkm pipeline: drain once, later reads hide under MFMAs ----
    LGKC(12);                  // aE + b0 landed; b1 + aO still in flight
    mfma8(aE, b0, 0, 0);
    LGKC(8);                   // b1 landed
    mfma8(aE, b1, 0, 1);
    LGKC(0);                   // aO landed
    mfma8(aO, b1, 1, 1);
    mfma8(aO, b0, 1, 0);
    // advance (ky,kx) by 64 (single conditional; 64 < KYP so at most one carry)
    kxN += 64; if (kxN >= KYP){ kxN -= KYP; ++kyN; }
    // tile boundary: next tile's buffers fully landed, then all-waves sync
    WAITV(0);
    BARRIER();
  }

  // ---- epilogue: C store ----
  const int m_base = mblk*256 + wr*128;
  const int n_base = nblk*256 + wn*64;
  const int rsub = (lane >> 4) << 2;
  const int csub = lane & 15;
#pragma unroll
  for (int mf = 0; mf < 8; ++mf)
#pragma unroll
    for (int nf = 0; nf < 4; ++nf)
#pragma unroll
      for (int j = 0; j < 4; ++j){
        int m = m_base + mf*16 + rsub + j;
        int n = n_base + nf*16 + csub;
        ys[(size_t)m*1024 + n] = f2bf(acc[mf][nf][j]);
      }
}

// ---------------- mix (MFMA): block = (b, oy); 32 ys rows x 8 r = 256 rho rows ----------------
__global__ __launch_bounds__(512) void mix_kernel(const u16* __restrict__ ys,
    const float* __restrict__ b1, const float* __restrict__ w2, const float* __restrict__ b2,
    const float* __restrict__ wa, const float* __restrict__ ba,
    const float* __restrict__ wr, const float* __restrict__ br,
    const float* __restrict__ wz, const float* __restrict__ bz,
    float* __restrict__ out){
  __shared__ __align__(16) u16 Ah[256*128];    // 64 KB: xa then h (both swizzled)
  __shared__ __align__(16) u16 W2s[128*128];   // 32 KB
  __shared__ __align__(16) u16 Wcs[80*128];    // 20 KB
  __shared__ float b2s[128];
  __shared__ float bcs[80];

  const int blk = blockIdx.x;
  const int b   = blk >> 5, oy = blk & 31;
  const int t    = threadIdx.x;
  const int lane = t & 63;
  const int w    = t >> 6;              // wave = rotation r

  // ---- stage xa = leaky(ys + b1) -> Ah (swizzled bf16) ----
  {
    const int kn0 = (t & 15)*8;
    const int r_  = (t >> 4) & 7;
    float b1v[8];
#pragma unroll
    for (int j = 0; j < 8; ++j) b1v[j] = b1[kn0 + j];
#pragma unroll
    for (int i = 0; i < 8; ++i){
      int m_loc = 4*i + (t >> 7);       // 0..31 == ox
      int row_m = (((b >> 2)*32 + m_loc)*128) + (b & 3)*32 + oy;   // gemm m-mapping
      uint4 v = *(const uint4*)(ys + (size_t)row_m*1024 + r_*128 + kn0);
      u32 vv[4] = {v.x, v.y, v.z, v.w};
      u16 hh[8];
#pragma unroll
      for (int j = 0; j < 4; ++j){
        float lo = __uint_as_float(vv[j] << 16);
        float hi = __uint_as_float(vv[j] & 0xFFFF0000u);
        hh[2*j]   = f2bf(leaky_(lo + b1v[2*j]));
        hh[2*j+1] = f2bf(leaky_(hi + b1v[2*j+1]));
      }
      int Arow = r_*32 + m_loc;
      int off = (Arow*256 + kn0*2) ^ ((Arow & 7) << 4);
      uint4 pk;
      pk.x = (u32)hh[0] | ((u32)hh[1] << 16);
      pk.y = (u32)hh[2] | ((u32)hh[3] << 16);
      pk.z = (u32)hh[4] | ((u32)hh[5] << 16);
      pk.w = (u32)hh[6] | ((u32)hh[7] << 16);
      *(uint4*)((char*)Ah + off) = pk;
    }
  }
  // ---- stage w2 -> W2s ----
#pragma unroll
  for (int i = 0; i < 4; ++i){
    int ch = i*512 + t;                 // 2048 chunks
    int row = ch >> 4, kn0 = (ch & 15)*8;
    const float* src = w2 + row*128 + kn0;
    u16 hh[8];
#pragma unroll
    for (int j = 0; j < 8; ++j) hh[j] = f2bf(src[j]);
    int off = (row*256 + kn0*2) ^ ((row & 7) << 4);
    uint4 pk;
    pk.x = (u32)hh[0] | ((u32)hh[1] << 16);
    pk.y = (u32)hh[2] | ((u32)hh[3] << 16);
    pk.z = (u32)hh[4] | ((u32)hh[5] << 16);
    pk.w = (u32)hh[6] | ((u32)hh[7] << 16);
    *(uint4*)((char*)W2s + off) = pk;
  }
  // ---- stage Wcat -> Wcs : rows 0..63 wz, 64 wa, 65/66 wr, 67..79 zero ----
#pragma unroll
  for (int i = 0; i < 3; ++i){
    int ch = i*512 + t;                 // 1280 chunks
    if (ch < 1280){
      int row = ch >> 4, kn0 = (ch & 15)*8;
      const float* src = nullptr;
      if (row < 64)      src = wz + row*128 + kn0;
      else if (row == 64) src = wa + kn0;
      else if (row == 65) src = wr + kn0;
      else if (row == 66) src = wr + 128 + kn0;
      u16 hh[8];
#pragma unroll
      for (int j = 0; j < 8; ++j) hh[j] = src ? f2bf(src[j]) : (u16)0;
      int off = (row*256 + kn0*2) ^ ((row & 7) << 4);
      uint4 pk;
      pk.x = (u32)hh[0] | ((u32)hh[1] << 16);
      pk.y = (u32)hh[2] | ((u32)hh[3] << 16);
      pk.z = (u32)hh[4] | ((u32)hh[5] << 16);
      pk.w = (u32)hh[6] | ((u32)hh[7] << 16);
      *(uint4*)((char*)Wcs + off) = pk;
    }
  }
  if (t < 128) b2s[t] = b2[t];
  if (t < 80){
    float v = 0.0f;
    if (t < 64) v = bz[t];
    else if (t == 64) v = ba[0];
    else if (t == 65) v = br[0];
    else if (t == 66) v = br[1];
    bcs[t] = v;
  }
  __syncthreads();

  // ---- GEMM1: h_pre = xa @ w2^T, wave w handles rows w*32..w*32+31 ----
  f32x4 acc1[2][8];
#pragma unroll
  for (int mf = 0; mf < 2; ++mf)
#pragma unroll
    for (int nf = 0; nf < 8; ++nf) acc1[mf][nf] = (f32x4){0.f,0.f,0.f,0.f};
#pragma unroll
  for (int kk = 0; kk < 128; kk += 32){
    int kb = (kk + ((lane >> 4) << 3))*2;
    bf16x8 a[2], bv[8];
#pragma unroll
    for (int mf = 0; mf < 2; ++mf){
      int row = w*32 + mf*16 + (lane & 15);
      int off = (row*256 + kb) ^ ((row & 7) << 4);
      a[mf] = *(const bf16x8*)((const char*)Ah + off);
    }
#pragma unroll
    for (int nf = 0; nf < 8; ++nf){
      int row = nf*16 + (lane & 15);
      int off = (row*256 + kb) ^ ((row & 7) << 4);
      bv[nf] = *(const bf16x8*)((const char*)W2s + off);
    }
#pragma unroll
    for (int mf = 0; mf < 2; ++mf)
#pragma unroll
      for (int nf = 0; nf < 8; ++nf)
        acc1[mf][nf] = __builtin_amdgcn_mfma_f32_16x16x32_bf16(a[mf], bv[nf], acc1[mf][nf], 0, 0, 0);
  }
  __syncthreads();   // all waves done reading Ah

  // ---- h = leaky(h_pre + b2) -> overwrite Ah (bf16, swizzled) ----
#pragma unroll
  for (int mf = 0; mf < 2; ++mf)
#pragma unroll
    for (int nf = 0; nf < 8; ++nf){
      int col = nf*16 + (lane & 15);
      float bb = b2s[col];
#pragma unroll
      for (int j = 0; j < 4; ++j){
        int row = w*32 + mf*16 + ((lane >> 4) << 2) + j;
        u16 hv = f2bf(leaky_(acc1[mf][nf][j] + bb));
        int off = (row*256 + col*2) ^ ((row & 7) << 4);
        *(u16*)((char*)Ah + off) = hv;
      }
    }
  __syncthreads();

  // ---- GEMM2: outs = h @ Wcat^T ----
  f32x4 acc2[2][5];
#pragma unroll
  for (int mf = 0; mf < 2; ++mf)
#pragma unroll
    for (int nf = 0; nf < 5; ++nf) acc2[mf][nf] = (f32x4){0.f,0.f,0.f,0.f};
#pragma unroll
  for (int kk = 0; kk < 128; kk += 32){
    int kb = (kk + ((lane >> 4) << 3))*2;
    bf16x8 a[2], bv[5];
#pragma unroll
    for (int mf = 0; mf < 2; ++mf){
      int row = w*32 + mf*16 + (lane & 15);
      int off = (row*256 + kb) ^ ((row & 7) << 4);
      a[mf] = *(const bf16x8*)((const char*)Ah + off);
    }
#pragma unroll
    for (int nf = 0; nf < 5; ++nf){
      int row = nf*16 + (lane & 15);
      int off = (row*256 + kb) ^ ((row & 7) << 4);
      bv[nf] = *(const bf16x8*)((const char*)Wcs + off);
    }
#pragma unroll
    for (int mf = 0; mf < 2; ++mf)
#pragma unroll
      for (int nf = 0; nf < 5; ++nf)
        acc2[mf][nf] = __builtin_amdgcn_mfma_f32_16x16x32_bf16(a[mf], bv[nf], acc2[mf][nf], 0, 0, 0);
  }

  // ---- epilogue: fused bias / p_r / offsets, direct stores ----
  const int r = w;
  float off_r = OFFS[r];
  float qn = off_r / 3.14159265358979323846f;
  float pr = -0.5f*qn*qn - 1.14472988584940017414f - 0.91893853320467274178f;
  const int pixb = oy*32;
#pragma unroll
  for (int mf = 0; mf < 2; ++mf)
#pragma unroll
    for (int nf = 0; nf < 5; ++nf){
      int c = nf*16 + (lane & 15);
#pragma unroll
      for (int j = 0; j < 4; ++j){
        int ox = mf*16 + ((lane >> 4) << 2) + j;
        float val = acc2[mf][nf][j];
        if (c < 64){
          out[OUT_Z + (size_t)b*524288 + (size_t)c*8192 + r*1024 + pixb + ox] = val + bcs[c];
        } else if (c == 64){
          out[OUT_ATTN + (size_t)(b*8 + r)*1024 + pixb + ox] = val + bcs[64] + pr;
        } else if (c == 65){
          out[OUT_TH + ((size_t)b*2)*8192 + r*1024 + pixb + ox] = val + bcs[65] + off_r;
        } else if (c == 66){
          out[OUT_TH + ((size_t)b*2 + 1)*8192 + r*1024 + pixb + ox] = val + bcs[66];
        }
      }
    }
}

// ---------------- softmax: per batch b, over 8192 attn values ----------------
__global__ __launch_bounds__(256) void softmax_kernel(const float* __restrict__ gumbel, float* __restrict__ out){
  __shared__ float a[8192];
  __shared__ float red[256];
  const int b = blockIdx.x, t = threadIdx.x;
  const float* attn = out + OUT_ATTN + (size_t)b*8192;
  float m = -3.0e38f;
  for (int i = t; i < 8192; i += 256){ float v = attn[i]; a[i] = v; m = fmaxf(m, v); }
  red[t] = m; __syncthreads();
#pragma unroll
  for (int s = 128; s > 0; s >>= 1){ if (t < s) red[t] = fmaxf(red[t], red[t+s]); __syncthreads(); }
  m = red[0]; __syncthreads();
  float s1 = 0.0f;
  for (int i = t; i < 8192; i += 256) s1 += expf(a[i] - m);
  red[t] = s1; __syncthreads();
#pragma unroll
  for (int s = 128; s > 0; s >>= 1){ if (t < s) red[t] += red[t+s]; __syncthreads(); }
  float lse = m + logf(red[0]);
  __syncthreads();
  float* q = out + OUT_QTR + (size_t)b*8192;
  for (int i = t; i < 8192; i += 256) q[i] = a[i] - lse;
  const float* g = gumbel + (size_t)b*8192;
  float m2 = -3.0e38f;
  for (int i = t; i < 8192; i += 256){ float v = a[i] + g[i]; a[i] = v; m2 = fmaxf(m2, v); }
  __syncthreads();
  red[t] = m2; __syncthreads();
#pragma unroll
  for (int s = 128; s > 0; s >>= 1){ if (t < s) red[t] = fmaxf(red[t], red[t+s]); __syncthreads(); }
  m2 = red[0]; __syncthreads();
  float s2 = 0.0f;
  for (int i = t; i < 8192; i += 256) s2 += expf(a[i] - m2);
  red[t] = s2; __syncthreads();
#pragma unroll
  for (int s = 128; s > 0; s >>= 1){ if (t < s) red[t] += red[t+s]; __syncthreads(); }
  float inv = 1.0f/red[0];
  float* as_ = out + OUT_AS + (size_t)b*8192;
  for (int i = t; i < 8192; i += 256) as_[i] = expf(a[i] - m2)*inv;
}

// ---------------- tiny: p_r and offsets ----------------
__global__ void tiny_kernel(float* __restrict__ out){
  int t = threadIdx.x;
  if (t < 8){
    float off = OFFS[t];
    out[OUT_OFF + t] = off;
    float qn = off / 3.14159265358979323846f;
    out[OUT_PR + t] = -0.5f*qn*qn - 1.14472988584940017414f - 0.91893853320467274178f;
  }
}

extern "C" void kernel_launch(void* const* d_in, const int* in_sizes, int n_in,
                              void* d_out, int out_size, void* d_ws, size_t ws_size,
                              hipStream_t stream){
  const float* x      = (const float*)d_in[0];
  const float* w1     = (const float*)d_in[1];
  const float* b1     = (const float*)d_in[2];
  const float* w2     = (const float*)d_in[3];
  const float* b2     = (const float*)d_in[4];
  const float* wa     = (const float*)d_in[5];
  const float* ba     = (const float*)d_in[6];
  const float* wr     = (const float*)d_in[7];
  const float* br     = (const float*)d_in[8];
  const float* wz     = (const float*)d_in[9];
  const float* bz     = (const float*)d_in[10];
  const float* gumbel = (const float*)d_in[11];
  float* out = (float*)d_out;

  // workspace layout (bytes):
  // twb : 1024*4736*2      =  9,699,328
  // xsh : 8*32*96*128*2    =  6,291,456
  // ys  : 32768*1024*2     = 67,108,864
  u16* twb = (u16*)d_ws;
  u16* xsh = twb + (size_t)1024*KPAD;
  u16* ys  = xsh + (size_t)8*32*96*128;

  xshift_kernel <<<1536, 256, 0, stream>>>(x, xsh);
  rotate_kernel <<<1024, 256, 0, stream>>>(w1, twb);
  gemm_kernel   <<<512,  512, 0, stream>>>(xsh, twb, ys);
  mix_kernel    <<<1024, 512, 0, stream>>>(ys, b1, w2, b2, wa, ba, wr, br, wz, bz, out);
  softmax_kernel<<<32,   256, 0, stream>>>(gumbel, out);
  tiny_kernel   <<<1,    64,  0, stream>>>(out);
}

// Round 10
// 327.928 us; speedup vs baseline: 1.8437x; 1.8437x over previous
//
#include <hip/hip_runtime.h>
#include <hip/hip_bf16.h>

typedef unsigned int u32;
typedef unsigned short u16;

// Geometry: B=32, IC=1, N=64, KN=128, KS=65, PAD=16, R=8, LAT=32, HW=32
#define KYP 72            // kx padded 65 -> 72 per ky row (zero weights in pad)
#define KPAD 4736         // padded to 74*64
#define NK   74           // K-tiles of 64

// d_out element offsets (fp32)
#define OUT_ATTN 0
#define OUT_QTR  262144
#define OUT_PR   524288
#define OUT_AS   524296
#define OUT_OFF  786440
#define OUT_TH   786448
#define OUT_Z    1310736

typedef __attribute__((ext_vector_type(8))) short bf16x8;
typedef __attribute__((ext_vector_type(4))) float f32x4;

__device__ const float OFFS[8] = {
  0.0f,
  0.78539816339744830961f,
  1.57079632679489661923f,
  2.35619449019234492885f,
  3.14159265358979323846f,
 -2.35619449019234492885f,
 -1.57079632679489661923f,
 -0.78539816339744830961f
};

__device__ __forceinline__ float leaky_(float v){ return v >= 0.0f ? v : 0.01f*v; }

__device__ __forceinline__ u16 f2bf(float f){
  u32 x = __float_as_uint(f);
  u32 r = (x + 0x7FFFu + ((x >> 16) & 1u)) >> 16;   // RNE
  return (u16)r;
}

__device__ __forceinline__ void gload_lds16(const void* g, void* l){
  __builtin_amdgcn_global_load_lds((const __attribute__((address_space(1))) u32*)g,
                                   (__attribute__((address_space(3))) u32*)l, 16, 0, 0);
}

#define BARRIER() { asm volatile("" ::: "memory"); __builtin_amdgcn_s_barrier(); asm volatile("" ::: "memory"); }
#define WAITV(N)  asm volatile("s_waitcnt vmcnt(" #N ")" ::: "memory")
#define LGK0()    { asm volatile("s_waitcnt lgkmcnt(0)" ::: "memory"); __builtin_amdgcn_sched_barrier(0); }

// ---------------- prep: blocks 0..1023 rotate w1 -> twb; blocks 1024..2559 xshift ----------------
__global__ __launch_bounds__(256) void prep_kernel(const float* __restrict__ x, u16* __restrict__ xsh,
                                                   const float* __restrict__ w1, u16* __restrict__ twb){
  __shared__ float wsh[4225];
  if (blockIdx.x < 1024){
    // ---- rotate: w1(128,65,65) -> twb[n=rot*128+kn][KPAD] bf16 ----
    int n = blockIdx.x;          // 0..1023
    int kn = n & 127, rot = n >> 7;
    for (int i = threadIdx.x; i < 4225; i += 256) wsh[i] = w1[kn*4225 + i];
    __syncthreads();
    float th  = 0.78539816339744830961f * (float)rot;
    float cth = cosf(th), sth = sinf(th);
    for (int t = threadIdx.x; t < KPAD; t += 256){
      int ky = t / KYP, kx = t - ky*KYP;
      u16 outv = 0;
      if (ky < 65 && kx < 65){
        float yy = (2.0f*(float)ky + 1.0f)/65.0f - 1.0f;
        float xx = (2.0f*(float)kx + 1.0f)/65.0f - 1.0f;
        float xs  =  cth*xx + sth*yy;
        float ysv = -sth*xx + cth*yy;
        float px = ((xs  + 1.0f)*65.0f - 1.0f)*0.5f;
        float py = ((ysv + 1.0f)*65.0f - 1.0f)*0.5f;
        float x0 = floorf(px), y0 = floorf(py);
        float wx = px - x0, wy = py - y0;
        auto samp = [&](float yf, float xf)->float{
          bool valid = (yf >= 0.0f) && (yf < 65.0f) && (xf >= 0.0f) && (xf < 65.0f);
          int yc = (int)fminf(fmaxf(yf, 0.0f), 64.0f);
          int xc = (int)fminf(fmaxf(xf, 0.0f), 64.0f);
          return valid ? wsh[yc*65 + xc] : 0.0f;
        };
        float val = samp(y0,      x0     )*(1.0f-wy)*(1.0f-wx)
                  + samp(y0,      x0+1.0f)*(1.0f-wy)*wx
                  + samp(y0+1.0f, x0     )*wy*(1.0f-wx)
                  + samp(y0+1.0f, x0+1.0f)*wy*wx;
        outv = f2bf(val);
      }
      twb[(size_t)n*KPAD + t] = outv;
    }
  } else {
    // ---- xshift: x(32,64,64) f32 -> xsh[s=8][b=32][row=96][col=128] bf16 ----
    int t = (blockIdx.x - 1024)*256 + threadIdx.x;    // 393216 threads, 16B each
    if (t >= 393216) return;
    int c8  = t & 15;
    int u   = t >> 4;
    int row = u % 96;
    int v   = u / 96;
    int b   = v & 31;
    int s   = v >> 5;
    int iy = row - 16;
    u16 h[8];
#pragma unroll
    for (int j = 0; j < 8; ++j){
      int ix = c8*8 + j + s - 16;
      float val = 0.0f;
      if (iy >= 0 && iy < 64 && ix >= 0 && ix < 64) val = x[(b*64 + iy)*64 + ix];
      h[j] = f2bf(val);
    }
    uint4 pk;
    pk.x = (u32)h[0] | ((u32)h[1] << 16);
    pk.y = (u32)h[2] | ((u32)h[3] << 16);
    pk.z = (u32)h[4] | ((u32)h[5] << 16);
    pk.w = (u32)h[6] | ((u32)h[7] << 16);
    ((uint4*)xsh)[t] = pk;
  }
}

// ---------------- implicit-GEMM conv, 256^2, ONE barrier per K-tile (R7, 251 us) ----------------
// m = mblk*256 + lm (ox pair-major);  n = nblk*256 + ln.  512 thr = 8 waves (2M x 4N).
// Per tile: {reads+stage, lgkm-fenced MFMA clusters} free-flow per wave; single
// WAITV(0)+barrier at the tile boundary (loads were issued 2-3 phases earlier).
// NOTE (R8/R9 post-mortem): deeper in-wave pipelining spills — acc uses 128 AGPR,
// arch-VGPR budget is 128; R7's 12-fragment live set fits (VGPR=120), 24 doesn't.
__global__ __launch_bounds__(512, 2) void gemm_kernel(const u16* __restrict__ xsh,
                                                      const u16* __restrict__ twb,
                                                      u16* __restrict__ ys){
  __shared__ u16 AsB[2*16384];   // [buf][256 rows][64 k] swizzled, 64 KB
  __shared__ u16 BsB[2*16384];   // 64 KB

  const int bid  = blockIdx.x;
  const int nblk = bid & 3, mblk = bid >> 2;
  const int t    = threadIdx.x;
  const int lane = t & 63, w = t >> 6;
  const int wr   = w >> 2, wn = w & 3;        // wave tile: rows wr*128, cols wn*64
  const int hi8  = (lane >> 4) << 3;

  // ---- staging thread mapping (per 8KB call c: rows c*64 + sr, cols j0e..j0e+7) ----
  const int sr  = t >> 3;
  const int j0e = (t & 7) * 8;
  const int jsw = j0e ^ ((sr & 7) << 3);      // source pre-swizzle (T2, both-sides)
  const int bg  = mblk >> 4;
  const int ox2 = (mblk & 15) * 2;
  int aOff[4];
#pragma unroll
  for (int c = 0; c < 4; ++c){
    int i  = c*64 + sr;                       // local m row
    int ox = ox2 + (i >> 7);
    int s_ = ox & 7, colb = ox & ~7;
    int b_ = (bg << 2) + ((i & 127) >> 5);
    int oy = i & 31;
    aOff[c] = ((s_*32 + b_)*96 + oy)*128 + colb;
  }
  const u16* bPtr[4];
#pragma unroll
  for (int c = 0; c < 4; ++c){
    int nloc = c*64 + sr;
    bPtr[c] = twb + (size_t)(nblk*256 + nloc)*KPAD + jsw;
  }

  auto stageA4 = [&](int ky, int kx0, u16* dstbase){
    bool pad = (ky >= 65);
    int kofs = ky*128 + kx0;
#pragma unroll
    for (int c = 0; c < 4; ++c){
      int gofs = pad ? 0 : (aOff[c] + kofs);
      gload_lds16(xsh + gofs, dstbase + c*4096 + w*512);
    }
  };
  auto stageB4 = [&](int kt, u16* dstbase){
    int ktc = (kt < NK) ? kt : (NK-1);        // ghost tile: re-read valid data
#pragma unroll
    for (int c = 0; c < 4; ++c)
      gload_lds16(bPtr[c] + ktc*64, dstbase + c*4096 + w*512);
  };

  f32x4 acc[8][4];
#pragma unroll
  for (int i = 0; i < 8; ++i)
#pragma unroll
    for (int j = 0; j < 4; ++j) acc[i][j] = (f32x4){0.f,0.f,0.f,0.f};
  bf16x8 amat[4][2], bmat[4][2];

  auto readA = [&](int mh, const char* Ab){
#pragma unroll
    for (int mj = 0; mj < 4; ++mj){
      int row = wr*128 + mh*64 + mj*16 + (lane & 15);
#pragma unroll
      for (int kk = 0; kk < 2; ++kk){
        int off = (row*128 + (kk*32 + hi8)*2) ^ ((row & 7) << 4);
        amat[mj][kk] = *(const bf16x8*)(Ab + off);
      }
    }
  };
  auto readB = [&](int nh, const char* Bb){
#pragma unroll
    for (int jn = 0; jn < 2; ++jn){
      int row = wn*64 + (nh*2 + jn)*16 + (lane & 15);
#pragma unroll
      for (int kk = 0; kk < 2; ++kk){
        int off = (row*128 + (kk*32 + hi8)*2) ^ ((row & 7) << 4);
        bmat[nh*2 + jn][kk] = *(const bf16x8*)(Bb + off);
      }
    }
  };
  auto mfma16 = [&](int MH, int NH){
    __builtin_amdgcn_s_setprio(1);
#pragma unroll
    for (int mj = 0; mj < 4; ++mj)
#pragma unroll
      for (int jn = 0; jn < 2; ++jn)
#pragma unroll
        for (int kk = 0; kk < 2; ++kk)
          acc[MH*4+mj][NH*2+jn] = __builtin_amdgcn_mfma_f32_16x16x32_bf16(
              amat[mj][kk], bmat[NH*2+jn][kk], acc[MH*4+mj][NH*2+jn], 0, 0, 0);
    __builtin_amdgcn_s_setprio(0);
  };

  u16* const A0 = AsB;
  u16* const B0 = BsB;
  u16* const A1 = AsB + 16384;
  u16* const B1 = BsB + 16384;

  // ---- prologue: stage K-tile 0 -> buffer 0 (kt=0: ky=0, kx=jsw; no division) ----
  stageB4(0, B0);
  stageA4(0, jsw, A0);
  // incremental (ky,kx) state for the next A-stage (kt=1): k = 64 + jsw
  int kyN = (64 + jsw >= KYP) ? 1 : 0;
  int kxN = 64 + jsw - (kyN ? KYP : 0);
  WAITV(0);
  BARRIER();

  for (int kt = 0; kt < NK; ++kt){
    u16* Ab = (kt & 1) ? A1 : A0;
    u16* Bb = (kt & 1) ? B1 : B0;
    u16* An = (kt & 1) ? A0 : A1;
    u16* Bn = (kt & 1) ? B0 : B1;
    // ph1: reads for (0,0); stage next-tile B
    readA(0, (const char*)Ab); readB(0, (const char*)Bb);
    stageB4(kt+1, Bn);
    LGK0();
    mfma16(0, 0);
    // ph2: reads for (0,1); stage next-tile A
    readB(1, (const char*)Bb);
    stageA4(kyN, kxN, An);
    LGK0();
    mfma16(0, 1);
    // ph3: reads for (1,1)
    readA(1, (const char*)Ab);
    LGK0();
    mfma16(1, 1);
    // ph4
    mfma16(1, 0);
    // advance (ky,kx) by 64 (single conditional; 64 < KYP so at most one carry)
    kxN += 64; if (kxN >= KYP){ kxN -= KYP; ++kyN; }
    // tile boundary: next tile's buffers fully landed, then all-waves sync
    WAITV(0);
    BARRIER();
  }

  // ---- epilogue: C store ----
  const int m_base = mblk*256 + wr*128;
  const int n_base = nblk*256 + wn*64;
  const int rsub = (lane >> 4) << 2;
  const int csub = lane & 15;
#pragma unroll
  for (int mf = 0; mf < 8; ++mf)
#pragma unroll
    for (int nf = 0; nf < 4; ++nf)
#pragma unroll
      for (int j = 0; j < 4; ++j){
        int m = m_base + mf*16 + rsub + j;
        int n = n_base + nf*16 + csub;
        ys[(size_t)m*1024 + n] = f2bf(acc[mf][nf][j]);
      }
}

// ---------------- mix (MFMA): block = (b, oy); 32 ys rows x 8 r = 256 rho rows ----------------
__global__ __launch_bounds__(512) void mix_kernel(const u16* __restrict__ ys,
    const float* __restrict__ b1, const float* __restrict__ w2, const float* __restrict__ b2,
    const float* __restrict__ wa, const float* __restrict__ ba,
    const float* __restrict__ wr, const float* __restrict__ br,
    const float* __restrict__ wz, const float* __restrict__ bz,
    float* __restrict__ out){
  __shared__ __align__(16) u16 Ah[256*128];    // 64 KB: xa then h (both swizzled)
  __shared__ __align__(16) u16 W2s[128*128];   // 32 KB
  __shared__ __align__(16) u16 Wcs[80*128];    // 20 KB
  __shared__ float b2s[128];
  __shared__ float bcs[80];

  const int blk = blockIdx.x;
  const int b   = blk >> 5, oy = blk & 31;
  const int t    = threadIdx.x;
  const int lane = t & 63;
  const int w    = t >> 6;              // wave = rotation r

  // ---- stage xa = leaky(ys + b1) -> Ah (swizzled bf16) ----
  {
    const int kn0 = (t & 15)*8;
    const int r_  = (t >> 4) & 7;
    float b1v[8];
#pragma unroll
    for (int j = 0; j < 8; ++j) b1v[j] = b1[kn0 + j];
#pragma unroll
    for (int i = 0; i < 8; ++i){
      int m_loc = 4*i + (t >> 7);       // 0..31 == ox
      int row_m = (((b >> 2)*32 + m_loc)*128) + (b & 3)*32 + oy;   // gemm m-mapping
      uint4 v = *(const uint4*)(ys + (size_t)row_m*1024 + r_*128 + kn0);
      u32 vv[4] = {v.x, v.y, v.z, v.w};
      u16 hh[8];
#pragma unroll
      for (int j = 0; j < 4; ++j){
        float lo = __uint_as_float(vv[j] << 16);
        float hi = __uint_as_float(vv[j] & 0xFFFF0000u);
        hh[2*j]   = f2bf(leaky_(lo + b1v[2*j]));
        hh[2*j+1] = f2bf(leaky_(hi + b1v[2*j+1]));
      }
      int Arow = r_*32 + m_loc;
      int off = (Arow*256 + kn0*2) ^ ((Arow & 7) << 4);
      uint4 pk;
      pk.x = (u32)hh[0] | ((u32)hh[1] << 16);
      pk.y = (u32)hh[2] | ((u32)hh[3] << 16);
      pk.z = (u32)hh[4] | ((u32)hh[5] << 16);
      pk.w = (u32)hh[6] | ((u32)hh[7] << 16);
      *(uint4*)((char*)Ah + off) = pk;
    }
  }
  // ---- stage w2 -> W2s ----
#pragma unroll
  for (int i = 0; i < 4; ++i){
    int ch = i*512 + t;                 // 2048 chunks
    int row = ch >> 4, kn0 = (ch & 15)*8;
    const float* src = w2 + row*128 + kn0;
    u16 hh[8];
#pragma unroll
    for (int j = 0; j < 8; ++j) hh[j] = f2bf(src[j]);
    int off = (row*256 + kn0*2) ^ ((row & 7) << 4);
    uint4 pk;
    pk.x = (u32)hh[0] | ((u32)hh[1] << 16);
    pk.y = (u32)hh[2] | ((u32)hh[3] << 16);
    pk.z = (u32)hh[4] | ((u32)hh[5] << 16);
    pk.w = (u32)hh[6] | ((u32)hh[7] << 16);
    *(uint4*)((char*)W2s + off) = pk;
  }
  // ---- stage Wcat -> Wcs : rows 0..63 wz, 64 wa, 65/66 wr, 67..79 zero ----
#pragma unroll
  for (int i = 0; i < 3; ++i){
    int ch = i*512 + t;                 // 1280 chunks
    if (ch < 1280){
      int row = ch >> 4, kn0 = (ch & 15)*8;
      const float* src = nullptr;
      if (row < 64)      src = wz + row*128 + kn0;
      else if (row == 64) src = wa + kn0;
      else if (row == 65) src = wr + kn0;
      else if (row == 66) src = wr + 128 + kn0;
      u16 hh[8];
#pragma unroll
      for (int j = 0; j < 8; ++j) hh[j] = src ? f2bf(src[j]) : (u16)0;
      int off = (row*256 + kn0*2) ^ ((row & 7) << 4);
      uint4 pk;
      pk.x = (u32)hh[0] | ((u32)hh[1] << 16);
      pk.y = (u32)hh[2] | ((u32)hh[3] << 16);
      pk.z = (u32)hh[4] | ((u32)hh[5] << 16);
      pk.w = (u32)hh[6] | ((u32)hh[7] << 16);
      *(uint4*)((char*)Wcs + off) = pk;
    }
  }
  if (t < 128) b2s[t] = b2[t];
  if (t < 80){
    float v = 0.0f;
    if (t < 64) v = bz[t];
    else if (t == 64) v = ba[0];
    else if (t == 65) v = br[0];
    else if (t == 66) v = br[1];
    bcs[t] = v;
  }
  __syncthreads();

  // ---- GEMM1: h_pre = xa @ w2^T, wave w handles rows w*32..w*32+31 ----
  f32x4 acc1[2][8];
#pragma unroll
  for (int mf = 0; mf < 2; ++mf)
#pragma unroll
    for (int nf = 0; nf < 8; ++nf) acc1[mf][nf] = (f32x4){0.f,0.f,0.f,0.f};
#pragma unroll
  for (int kk = 0; kk < 128; kk += 32){
    int kb = (kk + ((lane >> 4) << 3))*2;
    bf16x8 a[2], bv[8];
#pragma unroll
    for (int mf = 0; mf < 2; ++mf){
      int row = w*32 + mf*16 + (lane & 15);
      int off = (row*256 + kb) ^ ((row & 7) << 4);
      a[mf] = *(const bf16x8*)((const char*)Ah + off);
    }
#pragma unroll
    for (int nf = 0; nf < 8; ++nf){
      int row = nf*16 + (lane & 15);
      int off = (row*256 + kb) ^ ((row & 7) << 4);
      bv[nf] = *(const bf16x8*)((const char*)W2s + off);
    }
#pragma unroll
    for (int mf = 0; mf < 2; ++mf)
#pragma unroll
      for (int nf = 0; nf < 8; ++nf)
        acc1[mf][nf] = __builtin_amdgcn_mfma_f32_16x16x32_bf16(a[mf], bv[nf], acc1[mf][nf], 0, 0, 0);
  }
  __syncthreads();   // all waves done reading Ah

  // ---- h = leaky(h_pre + b2) -> overwrite Ah (bf16, swizzled) ----
#pragma unroll
  for (int mf = 0; mf < 2; ++mf)
#pragma unroll
    for (int nf = 0; nf < 8; ++nf){
      int col = nf*16 + (lane & 15);
      float bb = b2s[col];
#pragma unroll
      for (int j = 0; j < 4; ++j){
        int row = w*32 + mf*16 + ((lane >> 4) << 2) + j;
        u16 hv = f2bf(leaky_(acc1[mf][nf][j] + bb));
        int off = (row*256 + col*2) ^ ((row & 7) << 4);
        *(u16*)((char*)Ah + off) = hv;
      }
    }
  __syncthreads();

  // ---- GEMM2: outs = h @ Wcat^T ----
  f32x4 acc2[2][5];
#pragma unroll
  for (int mf = 0; mf < 2; ++mf)
#pragma unroll
    for (int nf = 0; nf < 5; ++nf) acc2[mf][nf] = (f32x4){0.f,0.f,0.f,0.f};
#pragma unroll
  for (int kk = 0; kk < 128; kk += 32){
    int kb = (kk + ((lane >> 4) << 3))*2;
    bf16x8 a[2], bv[5];
#pragma unroll
    for (int mf = 0; mf < 2; ++mf){
      int row = w*32 + mf*16 + (lane & 15);
      int off = (row*256 + kb) ^ ((row & 7) << 4);
      a[mf] = *(const bf16x8*)((const char*)Ah + off);
    }
#pragma unroll
    for (int nf = 0; nf < 5; ++nf){
      int row = nf*16 + (lane & 15);
      int off = (row*256 + kb) ^ ((row & 7) << 4);
      bv[nf] = *(const bf16x8*)((const char*)Wcs + off);
    }
#pragma unroll
    for (int mf = 0; mf < 2; ++mf)
#pragma unroll
      for (int nf = 0; nf < 5; ++nf)
        acc2[mf][nf] = __builtin_amdgcn_mfma_f32_16x16x32_bf16(a[mf], bv[nf], acc2[mf][nf], 0, 0, 0);
  }

  // ---- epilogue: fused bias / p_r / offsets, direct stores ----
  const int r = w;
  float off_r = OFFS[r];
  float qn = off_r / 3.14159265358979323846f;
  float pr = -0.5f*qn*qn - 1.14472988584940017414f - 0.91893853320467274178f;
  const int pixb = oy*32;
#pragma unroll
  for (int mf = 0; mf < 2; ++mf)
#pragma unroll
    for (int nf = 0; nf < 5; ++nf){
      int c = nf*16 + (lane & 15);
#pragma unroll
      for (int j = 0; j < 4; ++j){
        int ox = mf*16 + ((lane >> 4) << 2) + j;
        float val = acc2[mf][nf][j];
        if (c < 64){
          out[OUT_Z + (size_t)b*524288 + (size_t)c*8192 + r*1024 + pixb + ox] = val + bcs[c];
        } else if (c == 64){
          out[OUT_ATTN + (size_t)(b*8 + r)*1024 + pixb + ox] = val + bcs[64] + pr;
        } else if (c == 65){
          out[OUT_TH + ((size_t)b*2)*8192 + r*1024 + pixb + ox] = val + bcs[65] + off_r;
        } else if (c == 66){
          out[OUT_TH + ((size_t)b*2 + 1)*8192 + r*1024 + pixb + ox] = val + bcs[66];
        }
      }
    }
}

// ---------------- softmax (1024 thr) + fused tiny: per batch b over 8192 attn values ----------------
__global__ __launch_bounds__(1024) void softmax_kernel(const float* __restrict__ gumbel, float* __restrict__ out){
  __shared__ float a[8192];
  __shared__ float red[1024];
  const int b = blockIdx.x, t = threadIdx.x;
  if (b == 0 && t < 8){
    float off = OFFS[t];
    out[OUT_OFF + t] = off;
    float qn = off / 3.14159265358979323846f;
    out[OUT_PR + t] = -0.5f*qn*qn - 1.14472988584940017414f - 0.91893853320467274178f;
  }
  const float* attn = out + OUT_ATTN + (size_t)b*8192;
  float m = -3.0e38f;
  for (int i = t; i < 8192; i += 1024){ float v = attn[i]; a[i] = v; m = fmaxf(m, v); }
  red[t] = m; __syncthreads();
#pragma unroll
  for (int s = 512; s > 0; s >>= 1){ if (t < s) red[t] = fmaxf(red[t], red[t+s]); __syncthreads(); }
  m = red[0]; __syncthreads();
  float s1 = 0.0f;
  for (int i = t; i < 8192; i += 1024) s1 += expf(a[i] - m);
  red[t] = s1; __syncthreads();
#pragma unroll
  for (int s = 512; s > 0; s >>= 1){ if (t < s) red[t] += red[t+s]; __syncthreads(); }
  float lse = m + logf(red[0]);
  __syncthreads();
  float* q = out + OUT_QTR + (size_t)b*8192;
  for (int i = t; i < 8192; i += 1024) q[i] = a[i] - lse;
  const float* g = gumbel + (size_t)b*8192;
  float m2 = -3.0e38f;
  for (int i = t; i < 8192; i += 1024){ float v = a[i] + g[i]; a[i] = v; m2 = fmaxf(m2, v); }
  __syncthreads();
  red[t] = m2; __syncthreads();
#pragma unroll
  for (int s = 512; s > 0; s >>= 1){ if (t < s) red[t] = fmaxf(red[t], red[t+s]); __syncthreads(); }
  m2 = red[0]; __syncthreads();
  float s2 = 0.0f;
  for (int i = t; i < 8192; i += 1024) s2 += expf(a[i] - m2);
  red[t] = s2; __syncthreads();
#pragma unroll
  for (int s = 512; s > 0; s >>= 1){ if (t < s) red[t] += red[t+s]; __syncthreads(); }
  float inv = 1.0f/red[0];
  float* as_ = out + OUT_AS + (size_t)b*8192;
  for (int i = t; i < 8192; i += 1024) as_[i] = expf(a[i] - m2)*inv;
}

extern "C" void kernel_launch(void* const* d_in, const int* in_sizes, int n_in,
                              void* d_out, int out_size, void* d_ws, size_t ws_size,
                              hipStream_t stream){
  const float* x      = (const float*)d_in[0];
  const float* w1     = (const float*)d_in[1];
  const float* b1     = (const float*)d_in[2];
  const float* w2     = (const float*)d_in[3];
  const float* b2     = (const float*)d_in[4];
  const float* wa     = (const float*)d_in[5];
  const float* ba     = (const float*)d_in[6];
  const float* wr     = (const float*)d_in[7];
  const float* br     = (const float*)d_in[8];
  const float* wz     = (const float*)d_in[9];
  const float* bz     = (const float*)d_in[10];
  const float* gumbel = (const float*)d_in[11];
  float* out = (float*)d_out;

  // workspace layout (bytes):
  // twb : 1024*4736*2      =  9,699,328
  // xsh : 8*32*96*128*2    =  6,291,456
  // ys  : 32768*1024*2     = 67,108,864
  u16* twb = (u16*)d_ws;
  u16* xsh = twb + (size_t)1024*KPAD;
  u16* ys  = xsh + (size_t)8*32*96*128;

  prep_kernel   <<<2560, 256, 0, stream>>>(x, xsh, w1, twb);
  gemm_kernel   <<<512,  512, 0, stream>>>(xsh, twb, ys);
  mix_kernel    <<<1024, 512, 0, stream>>>(ys, b1, w2, b2, wa, ba, wr, br, wz, bz, out);
  softmax_kernel<<<32,  1024, 0, stream>>>(gumbel, out);
}